// Round 1
// 629.639 us; speedup vs baseline: 10.5017x; 10.5017x over previous
//
#include <hip/hip_runtime.h>

typedef __bf16 bf16;
typedef __bf16 bf16x4 __attribute__((ext_vector_type(4)));
typedef float  f32x4  __attribute__((ext_vector_type(4)));

#define NPTS 2048
#define XS_LD 68     // LDS stride for x / h tiles (64 + 4 pad: breaks 32-bank alignment)
#define W1_LD 100    // LDS stride for staged W1 rows (95 + zero pad to K=96 reads)

// ---------- dtype sniff: fp32 inputs reinterpreted as bf16 look like garbage ----------
__global__ __launch_bounds__(256) void k_sniff(const void* poses_raw, int* flag)
{
    __shared__ int cnt;
    if (threadIdx.x == 0) cnt = 0;
    __syncthreads();
    const bf16* pb = (const bf16*)poses_raw;
    int local = 0;
    for (int i = threadIdx.x; i < 9216; i += 256) {
        float v = (float)pb[i];
        if (!(v >= -2.0f && v <= 2.0f)) local++;
    }
    atomicAdd(&cnt, local);
    __syncthreads();
    if (threadIdx.x == 0) *flag = (cnt < 64) ? 1 : 0;
}

// ---------- encoder/decoder (verified, unchanged) ----------
template<typename T, int WANT>
__global__ __launch_bounds__(128) void k_encdec_t(
    const T* __restrict__ poses, const T* __restrict__ t_ped, const T* __restrict__ w,
    const T* __restrict__ Wec1, const T* __restrict__ bec1,
    const T* __restrict__ Wec21, const T* __restrict__ bec21,
    const T* __restrict__ Wec22, const T* __restrict__ bec22,
    const T* __restrict__ Wdc1, const T* __restrict__ bdc1,
    const T* __restrict__ Wdc21, const T* __restrict__ bdc21,
    const T* __restrict__ Wdc22, const T* __restrict__ bdc22,
    T* __restrict__ out_ei, T* __restrict__ out_delta,
    T* __restrict__ out_mean, T* __restrict__ out_logvar,
    const int* __restrict__ flag)
{
    if (*flag != WANT) return;
    int n = blockIdx.x, tid = threadIdx.x;
    __shared__ float sin_[88], zbuf[8], net1[64], din[80], net2[64];
    if (tid < 72)      sin_[tid] = (float)w[n*24 + tid/3] * (float)poses[n*72 + tid];
    else if (tid < 88) sin_[tid] = (float)t_ped[tid - 72];
    __syncthreads();
    if (tid < 64) {
        float a = (float)bec1[n*64 + tid];
        const T* wr = Wec1 + (size_t)(n*64 + tid) * 88;
        for (int c = 0; c < 88; ++c) a += (float)wr[c] * sin_[c];
        net1[tid] = fmaxf(a, 0.f);
    }
    __syncthreads();
    if (tid < 8) {
        float a = (float)bec21[n*8 + tid];
        const T* wr = Wec21 + (size_t)(n*8 + tid) * 64;
        for (int c = 0; c < 64; ++c) a += (float)wr[c] * net1[c];
        out_mean[n*8 + tid] = (T)a;
        zbuf[tid] = a;
    } else if (tid < 16) {
        int o = tid - 8;
        float a = (float)bec22[n*8 + o];
        const T* wr = Wec22 + (size_t)(n*8 + o) * 64;
        for (int c = 0; c < 64; ++c) a += (float)wr[c] * net1[c];
        out_logvar[n*8 + o] = (T)a;
    }
    __syncthreads();
    if (tid < 72)      din[tid] = sin_[tid];
    else if (tid < 80) din[tid] = zbuf[tid - 72];
    __syncthreads();
    if (tid < 64) {
        float a = (float)bdc1[n*64 + tid];
        const T* wr = Wdc1 + (size_t)(n*64 + tid) * 80;
        for (int c = 0; c < 80; ++c) a += (float)wr[c] * din[c];
        net2[tid] = fmaxf(a, 0.f);
    }
    __syncthreads();
    if (tid < 32) {
        float a = (float)bdc21[n*32 + tid];
        const T* wr = Wdc21 + (size_t)(n*32 + tid) * 64;
        for (int c = 0; c < 64; ++c) a += (float)wr[c] * net2[c];
        out_ei[n*32 + tid] = (T)a;
    } else if (tid < 35) {
        int o = tid - 32;
        float a = (float)bdc22[n*3 + o];
        const T* wr = Wdc22 + (size_t)(n*3 + o) * 64;
        for (int c = 0; c < 64; ++c) a += (float)wr[c] * net2[c];
        out_delta[n*3 + o] = (T)a;
    }
}

// ---------- blend weights (verified, unchanged) ----------
template<typename T, int WANT>
__global__ __launch_bounds__(256) void k_bweights_t(
    const T* __restrict__ wpts, const T* __restrict__ nodes,
    float* __restrict__ wgt, const int* __restrict__ flag)
{
    if (*flag != WANT) return;
    int v = blockIdx.x * 256 + threadIdx.x;
    float px = (float)wpts[v*3+0], py = (float)wpts[v*3+1], pz = (float)wpts[v*3+2];
    float denom = 0.f;
    for (int n = 0; n < 128; ++n) {
        float dx = px - (float)nodes[n*3+0];
        float dy = py - (float)nodes[n*3+1];
        float dz = pz - (float)nodes[n*3+2];
        float d2 = dx*dx + dy*dy + dz*dz;
        float influ = expf(-d2 * (1.0f/0.18f)) - 0.01f;
        denom += fmaxf(influ, 0.f) + 1e-7f;
    }
    float inv = 1.f / denom;
    for (int n = 0; n < 128; ++n) {
        float dx = px - (float)nodes[n*3+0];
        float dy = py - (float)nodes[n*3+1];
        float dz = pz - (float)nodes[n*3+2];
        float d2 = dx*dx + dy*dy + dz*dz;
        float influ = expf(-d2 * (1.0f/0.18f)) - 0.01f;
        wgt[n*NPTS + v] = (influ >= 0.f) ? (fmaxf(influ, 0.f) + 1e-7f) * inv : 0.f;
    }
}

// ---------- new fp32 register-blocked feature field ----------

__device__ __forceinline__ f32x4 loadw4(const float* p) { return *(const f32x4*)p; }
__device__ __forceinline__ f32x4 loadw4(const bf16* p)
{
    bf16x4 v = *(const bf16x4*)p;
    f32x4 r;
    #pragma unroll
    for (int j = 0; j < 4; ++j) r[j] = (float)v[j];
    return r;
}

// one 64->64 layer: W from global (row-major, K=64), x from LDS (k-major, stride XS_LD)
template<typename T>
__device__ __forceinline__ void layer64(
    const T* __restrict__ Wbase, const T* __restrict__ bbase,
    const float* __restrict__ hin, float* __restrict__ hout,
    int og, int pg)
{
    float acc[4][4] = {};
    #pragma unroll 4
    for (int k0 = 0; k0 < 64; k0 += 4) {
        f32x4 wv[4], xv[4];
        #pragma unroll
        for (int c = 0; c < 4; ++c) wv[c] = loadw4(Wbase + (size_t)(og*4 + c)*64 + k0);
        #pragma unroll
        for (int j = 0; j < 4; ++j) xv[j] = *(const f32x4*)&hin[(k0 + j)*XS_LD + pg*4];
        #pragma unroll
        for (int c = 0; c < 4; ++c)
            #pragma unroll
            for (int j = 0; j < 4; ++j)
                #pragma unroll
                for (int r = 0; r < 4; ++r)
                    acc[c][r] += wv[c][j] * xv[j][r];
    }
    #pragma unroll
    for (int c = 0; c < 4; ++c) {
        float b = (float)bbase[og*4 + c];
        f32x4 hv;
        #pragma unroll
        for (int r = 0; r < 4; ++r) hv[r] = fmaxf(acc[c][r] + b, 0.f);
        *(f32x4*)&hout[(og*4 + c)*XS_LD + pg*4] = hv;
    }
}

template<typename T, int WANT>
__global__ __launch_bounds__(256, 2) void k_feat_fast(
    const T* __restrict__ Wf1, const T* __restrict__ Wf2,
    const T* __restrict__ Wf3, const T* __restrict__ Wf4,
    const T* __restrict__ lc, const T* __restrict__ ei,
    const T* __restrict__ bf1, const T* __restrict__ bf2,
    const T* __restrict__ bf3, const T* __restrict__ bf4,
    const float* __restrict__ wgt, float* __restrict__ f_blend,
    const int* __restrict__ flag)
{
    if (*flag != WANT) return;
    int ptile = blockIdx.x;          // 32 tiles of 64 points
    int g     = blockIdx.y;          // 16 groups of 8 nodes
    int p0    = ptile * 64;
    int tid = threadIdx.x;
    int og = tid >> 4;               // 16 groups x 4 out-channels = 64
    int pg = tid & 15;               // 16 groups x 4 points       = 64

    // xs doubles as hB (rows 0..63); ws1 doubles as hC (stride XS_LD fits: 64*68 <= 64*100)
    __shared__ __attribute__((aligned(16))) float xs [96*XS_LD];  // 26.1 KB
    __shared__ __attribute__((aligned(16))) float ws1[64*W1_LD];  // 25.6 KB
    __shared__ __attribute__((aligned(16))) float hA [64*XS_LD];  // 17.4 KB

    if (tid < 64) xs[95*XS_LD + tid] = 0.f;   // pad row for K=96 layer-1 loop (never overwritten)

    float fb[4][4][4];
    #pragma unroll
    for (int a = 0; a < 4; ++a)
        #pragma unroll
        for (int b = 0; b < 4; ++b)
            #pragma unroll
            for (int r = 0; r < 4; ++r) fb[a][b][r] = 0.f;

    #pragma unroll 1
    for (int nn = 0; nn < 8; ++nn) {
        int n = g*8 + nn;
        __syncthreads();   // prev node's L4 reads of ws1(hC) done; xs(hB) free

        // stage ei -> xs rows 0..31 (broadcast over points)
        #pragma unroll
        for (int i = 0; i < 8; ++i) {
            int e = i*256 + tid; int r = e >> 6, p = e & 63;
            xs[r*XS_LD + p] = (float)ei[n*32 + r];
        }
        // stage lc -> xs rows 32..94 (coalesced global read, transposed LDS write)
        {
            const T* src = lc + ((size_t)n*NPTS + p0) * 63;
            #pragma unroll
            for (int i = 0; i < 16; ++i) {
                int e = i*256 + tid;
                if (e < 4032) {
                    int p = e / 63, c = e - p*63;
                    xs[(32 + c)*XS_LD + p] = (float)src[e];
                }
            }
        }
        // stage W1 (K=95 rows unaligned in global) -> ws1, padded col 95 = 0
        {
            const T* src = Wf1 + (size_t)n * 64 * 95;
            #pragma unroll
            for (int i = 0; i < 24; ++i) {
                int e = i*256 + tid;
                if (e < 6080) {
                    int oc = e / 95, k = e - oc*95;
                    ws1[oc*W1_LD + k] = (float)src[e];
                }
            }
            if (tid < 64) ws1[tid*W1_LD + 95] = 0.f;
        }
        float wgtv[4];
        #pragma unroll
        for (int j = 0; j < 4; ++j) wgtv[j] = wgt[n*NPTS + p0 + pg*4 + j];
        __syncthreads();

        // ---- L1: xs(95, padded to 96) x ws1 -> hA
        {
            float acc[4][4] = {};
            #pragma unroll 4
            for (int k0 = 0; k0 < 96; k0 += 4) {
                f32x4 wv[4], xv[4];
                #pragma unroll
                for (int c = 0; c < 4; ++c) wv[c] = *(const f32x4*)&ws1[(og*4 + c)*W1_LD + k0];
                #pragma unroll
                for (int j = 0; j < 4; ++j) xv[j] = *(const f32x4*)&xs[(k0 + j)*XS_LD + pg*4];
                #pragma unroll
                for (int c = 0; c < 4; ++c)
                    #pragma unroll
                    for (int j = 0; j < 4; ++j)
                        #pragma unroll
                        for (int r = 0; r < 4; ++r)
                            acc[c][r] += wv[c][j] * xv[j][r];
            }
            #pragma unroll
            for (int c = 0; c < 4; ++c) {
                float b = (float)bf1[n*64 + og*4 + c];
                f32x4 hv;
                #pragma unroll
                for (int r = 0; r < 4; ++r) hv[r] = fmaxf(acc[c][r] + b, 0.f);
                *(f32x4*)&hA[(og*4 + c)*XS_LD + pg*4] = hv;
            }
        }
        __syncthreads();

        // ---- L2: hA -> hB (= xs rows 0..63; xs free after L1)
        layer64(Wf2 + (size_t)n*64*64, bf2 + n*64, hA, xs, og, pg);
        __syncthreads();

        // ---- L3: hB(xs) -> hC (= ws1 region; W1 free after L1)
        layer64(Wf3 + (size_t)n*64*64, bf3 + n*64, xs, ws1, og, pg);
        __syncthreads();

        // ---- L4: hC(ws1) -> fb (256 out channels via 4 sweeps), weighted accumulate
        {
            const T* W4n = Wf4 + (size_t)n * 256 * 64;
            const T* b4n = bf4 + n * 256;
            #pragma unroll 1
            for (int mt = 0; mt < 4; ++mt) {
                float acc[4][4] = {};
                #pragma unroll 4
                for (int k0 = 0; k0 < 64; k0 += 4) {
                    f32x4 wv[4], xv[4];
                    #pragma unroll
                    for (int c = 0; c < 4; ++c)
                        wv[c] = loadw4(W4n + (size_t)(mt*64 + og*4 + c)*64 + k0);
                    #pragma unroll
                    for (int j = 0; j < 4; ++j)
                        xv[j] = *(const f32x4*)&ws1[(k0 + j)*XS_LD + pg*4];
                    #pragma unroll
                    for (int c = 0; c < 4; ++c)
                        #pragma unroll
                        for (int j = 0; j < 4; ++j)
                            #pragma unroll
                            for (int r = 0; r < 4; ++r)
                                acc[c][r] += wv[c][j] * xv[j][r];
                }
                #pragma unroll
                for (int c = 0; c < 4; ++c) {
                    float b = (float)b4n[mt*64 + og*4 + c];
                    #pragma unroll
                    for (int r = 0; r < 4; ++r)
                        fb[mt][c][r] += fmaxf(acc[c][r] + b, 0.f) * wgtv[r];
                }
            }
        }
    }

    // 16 node-groups accumulate into f_blend
    #pragma unroll
    for (int mt = 0; mt < 4; ++mt)
        #pragma unroll
        for (int c = 0; c < 4; ++c)
            #pragma unroll
            for (int r = 0; r < 4; ++r)
                atomicAdd(&f_blend[(size_t)(p0 + pg*4 + r)*256 + mt*64 + og*4 + c],
                          fb[mt][c][r]);
}

__global__ __launch_bounds__(256) void k_zero_fb(float* __restrict__ fb)
{
    fb[blockIdx.x*256 + threadIdx.x] = 0.f;
}

// ---------- Nerf head (verified, unchanged) ----------
template<typename T, int WANT>
__global__ __launch_bounds__(256) void k_head_t(
    const float* __restrict__ f_blend,
    const T* __restrict__ Wc1, const T* __restrict__ bc1,
    const T* __restrict__ Wc2, const T* __restrict__ bc2,
    const T* __restrict__ Wd1, const T* __restrict__ bd1,
    T* __restrict__ out_c, T* __restrict__ out_d,
    const int* __restrict__ flag)
{
    if (*flag != WANT) return;
    int t = blockIdx.x * 256 + threadIdx.x;
    int p = t >> 6, j = t & 63;
    const float* fb = f_blend + (size_t)p * 256;

    float a = (float)bc1[j];
    #pragma unroll 8
    for (int c = 0; c < 256; ++c)
        a += fb[c] * (float)Wc1[c*64 + j];
    float nc = fmaxf(a, 0.f);

    float s0 = nc * (float)Wc2[j*3 + 0];
    float s1 = nc * (float)Wc2[j*3 + 1];
    float s2 = nc * (float)Wc2[j*3 + 2];
    float sd = 0.f;
    #pragma unroll
    for (int u = 0; u < 4; ++u) {
        int c = j*4 + u;
        sd += fb[c] * (float)Wd1[c];
    }
    #pragma unroll
    for (int off = 32; off > 0; off >>= 1) {
        s0 += __shfl_down(s0, off);
        s1 += __shfl_down(s1, off);
        s2 += __shfl_down(s2, off);
        sd += __shfl_down(sd, off);
    }
    if (j == 0) {
        out_c[p*3 + 0] = (T)(s0 + (float)bc2[0]);
        out_c[p*3 + 1] = (T)(s1 + (float)bc2[1]);
        out_c[p*3 + 2] = (T)(s2 + (float)bc2[2]);
        out_d[p]       = (T)fmaxf(sd + (float)bd1[0], 0.f);
    }
}

extern "C" void kernel_launch(void* const* d_in, const int* in_sizes, int n_in,
                              void* d_out, int out_size, void* d_ws, size_t ws_size,
                              hipStream_t stream)
{
    char* wsp = (char*)d_ws;
    auto alloc = [&](size_t bytes) { char* r = wsp; wsp += (bytes + 255) & ~(size_t)255; return r; };
    float* f_blend = (float*)alloc((size_t)NPTS * 256 * 4);   // 2.10 MB
    float* wgt     = (float*)alloc((size_t)128 * NPTS * 4);   // 1.05 MB
    int*   flag    = (int*)  alloc(256);

    hipLaunchKernelGGL(k_sniff, dim3(1), dim3(256), 0, stream, d_in[0], flag);
    hipLaunchKernelGGL(k_zero_fb, dim3(2048), dim3(256), 0, stream, f_blend);

    #define LAUNCH_ALL(T, WANT)                                                         \
    {                                                                                   \
        const T* poses = (const T*)d_in[0];                                             \
        const T* t_ped = (const T*)d_in[1];                                             \
        const T* w     = (const T*)d_in[2];                                             \
        const T* wpts  = (const T*)d_in[3];                                             \
        const T* nodes = (const T*)d_in[4];                                             \
        const T* lc    = (const T*)d_in[5];                                             \
        const T* Wec1  = (const T*)d_in[6];  const T* bec1 = (const T*)d_in[7];         \
        const T* Wec21 = (const T*)d_in[8];  const T* bec21= (const T*)d_in[9];         \
        const T* Wec22 = (const T*)d_in[10]; const T* bec22= (const T*)d_in[11];        \
        const T* Wdc1  = (const T*)d_in[12]; const T* bdc1 = (const T*)d_in[13];        \
        const T* Wdc21 = (const T*)d_in[14]; const T* bdc21= (const T*)d_in[15];        \
        const T* Wdc22 = (const T*)d_in[16]; const T* bdc22= (const T*)d_in[17];        \
        const T* Wf1   = (const T*)d_in[18]; const T* bf1  = (const T*)d_in[19];        \
        const T* Wf2   = (const T*)d_in[20]; const T* bf2  = (const T*)d_in[21];        \
        const T* Wf3   = (const T*)d_in[22]; const T* bf3  = (const T*)d_in[23];        \
        const T* Wf4   = (const T*)d_in[24]; const T* bf4  = (const T*)d_in[25];        \
        const T* Wc1   = (const T*)d_in[26]; const T* bc1  = (const T*)d_in[27];        \
        const T* Wc2   = (const T*)d_in[28]; const T* bc2  = (const T*)d_in[29];        \
        const T* Wd1   = (const T*)d_in[30]; const T* bd1  = (const T*)d_in[31];        \
        T* out = (T*)d_out;                                                             \
        T* out_c      = out;                                                            \
        T* out_d      = out + 6144;                                                     \
        T* out_ei     = out + 8192;                                                     \
        T* out_delta  = out + 12288;                                                    \
        T* out_mean   = out + 12672;                                                    \
        T* out_logvar = out + 13696;                                                    \
        hipLaunchKernelGGL((k_encdec_t<T, WANT>), dim3(128), dim3(128), 0, stream,      \
            poses, t_ped, w, Wec1, bec1, Wec21, bec21, Wec22, bec22,                    \
            Wdc1, bdc1, Wdc21, bdc21, Wdc22, bdc22,                                     \
            out_ei, out_delta, out_mean, out_logvar, flag);                             \
        hipLaunchKernelGGL((k_bweights_t<T, WANT>), dim3(8), dim3(256), 0, stream,      \
            wpts, nodes, wgt, flag);                                                    \
        hipLaunchKernelGGL((k_feat_fast<T, WANT>), dim3(32, 16), dim3(256), 0, stream,  \
            Wf1, Wf2, Wf3, Wf4, lc, (const T*)out_ei, bf1, bf2, bf3, bf4,               \
            wgt, f_blend, flag);                                                        \
        hipLaunchKernelGGL((k_head_t<T, WANT>), dim3(512), dim3(256), 0, stream,        \
            f_blend, Wc1, bc1, Wc2, bc2, Wd1, bd1, out_c, out_d, flag);                 \
    }

    LAUNCH_ALL(bf16, 1)
    LAUNCH_ALL(float, 0)
    #undef LAUNCH_ALL
}